// Round 18
// baseline (246.374 us; speedup 1.0000x reference)
//
#include <hip/hip_runtime.h>

#define N_NODES 20000
#define N_EDGES 320000
#define NPAD    20032
#define NTILES  313         // NPAD/64
#define BN_EPS  1e-5f
#define NBLK    79          // ceil(20000/256)
#define CVTB    416         // 106496 threads / 256 for weight conversion

using bf16x8 = __attribute__((ext_vector_type(8))) short;
using f32x4  = __attribute__((ext_vector_type(4))) float;

__device__ __forceinline__ float bf2f(ushort u) {
  union { unsigned i; float f; } t; t.i = ((unsigned)u) << 16; return t.f;
}
__device__ __forceinline__ ushort f2bf(float f) {
  unsigned x = __float_as_uint(f);
  return (ushort)((x + 0x7fffu + ((x >> 16) & 1u)) >> 16);   // RNE
}

// bijective XCD-chunked swizzle (m204)
template <int NWG>
__device__ __forceinline__ int xcd_swz(int bid) {
  constexpr int Q = NWG / 8, R = NWG % 8;
  int xcd = bid & 7, pos = bid >> 3;
  return (xcd < R) ? (xcd * (Q + 1) + pos) : (R * (Q + 1) + (xcd - R) * Q + pos);
}

// ---------- fused: weights -> bf16 pool  +  degree count ----------
__global__ void k_prep(const float* s0, const float* s1, const float* s2,
                       const float* s3, const float* s4, const float* s5,
                       const float* s6, const float* s7, const float* s8,
                       const float* s9, ushort* __restrict__ wdst,
                       const int* __restrict__ edst, int* __restrict__ deg) {
  int b = blockIdx.x;
  if (b < CVTB) {
    int e = (b * 256 + threadIdx.x) * 4;
    if (e >= 425984) return;
    const float* s; int off;
    if      (e < 16384)  { s = s0; off = e; }
    else if (e < 49152)  { s = s1; off = e - 16384; }
    else if (e < 81920)  { s = s2; off = e - 49152; }
    else if (e < 147456) { s = s3; off = e - 81920; }
    else if (e < 212992) { s = s4; off = e - 147456; }
    else if (e < 278528) { s = s5; off = e - 212992; }
    else if (e < 344064) { s = s6; off = e - 278528; }
    else if (e < 376832) { s = s7; off = e - 344064; }
    else if (e < 409600) { s = s8; off = e - 376832; }
    else                 { s = s9; off = e - 409600; }
    float4 v = *(const float4*)(s + off);
    wdst[e + 0] = f2bf(v.x); wdst[e + 1] = f2bf(v.y);
    wdst[e + 2] = f2bf(v.z); wdst[e + 3] = f2bf(v.w);
  } else {
    int t = (b - CVTB) * 256 + threadIdx.x;
    if (t < N_EDGES) {
      unsigned d = (unsigned)edst[t];
      if (d < N_NODES) atomicAdd(&deg[d], 1);
    }
  }
}

// ---------- CSR scan ----------
__global__ void k_scanA(const int* __restrict__ deg, int* __restrict__ part,
                        int* __restrict__ bsum) {
  __shared__ int buf[256];
  int i = blockIdx.x * 256 + threadIdx.x;
  int v = (i < N_NODES) ? deg[i] : 0;
  buf[threadIdx.x] = v;
  __syncthreads();
  #pragma unroll
  for (int s = 1; s < 256; s <<= 1) {
    int t = (threadIdx.x >= s) ? buf[threadIdx.x - s] : 0;
    __syncthreads();
    buf[threadIdx.x] += t;
    __syncthreads();
  }
  if (i < N_NODES) part[i] = buf[threadIdx.x];
  if (threadIdx.x == 255) bsum[blockIdx.x] = buf[255];
}

__global__ void k_scanC(const int* __restrict__ deg, const int* __restrict__ part,
                        const int* __restrict__ bsum, int* __restrict__ rowptr,
                        int* __restrict__ cursor, float* __restrict__ inv) {
  __shared__ int soff;
  if (threadIdx.x == 0) {
    int o = 0;
    for (int b = 0; b < blockIdx.x; ++b) o += bsum[b];
    soff = o;
  }
  __syncthreads();
  int i = blockIdx.x * 256 + threadIdx.x;
  if (i >= N_NODES) return;
  int r1 = soff + part[i];
  int d = deg[i];
  rowptr[i + 1] = r1;
  cursor[i] = r1 - d;
  if (i == 0) rowptr[0] = 0;
  inv[i] = 1.0f / (float)max(d, 1);
}

__global__ void k_fill(const int* __restrict__ src, const int* __restrict__ dst,
                       int* __restrict__ cursor, int* __restrict__ col) {
  int e = blockIdx.x * blockDim.x + threadIdx.x;
  if (e >= N_EDGES) return;
  unsigned d = (unsigned)dst[e];
  if (d >= N_NODES) return;
  int p = atomicAdd(&cursor[d], 1);
  col[p] = src[e];
}

// ---------- gather-mean, 16B/lane, multi-neighbor per wave-iter ----------
template <int DIM, bool BN>
__global__ __launch_bounds__(256) void k_gather(
    const ushort* __restrict__ z, const int* __restrict__ rowptr,
    const int* __restrict__ col, const float* __restrict__ inv,
    const float* __restrict__ bnp, ushort* __restrict__ mean) {
  constexpr int LPR = DIM / 8;
  constexpr int NPW = 64 / LPR;
  int node = blockIdx.x * 4 + (threadIdx.x >> 6);
  if (node >= N_NODES) return;
  int lane = threadIdx.x & 63;
  int grp = lane / LPR;
  int sub = lane % LPR;
  float sc[8], sh[8];
  if constexpr (BN) {
    #pragma unroll
    for (int k = 0; k < 8; ++k) {
      sc[k] = bnp[sub * 8 + k];
      sh[k] = bnp[256 + sub * 8 + k];
    }
  }
  float acc[8] = {};
  int r0 = rowptr[node], r1 = rowptr[node + 1];
  #pragma unroll 2
  for (int j = r0; j < r1; j += NPW) {
    int jj = j + grp;
    bool val = jj < r1;
    int nb = val ? col[jj] : 0;
    bf16x8 v = *(const bf16x8*)(z + (size_t)nb * DIM + sub * 8);
    float w = val ? 1.f : 0.f;
    #pragma unroll
    for (int k = 0; k < 8; ++k) {
      float f = bf2f((ushort)v[k]);
      if constexpr (BN) f = fmaxf(f * sc[k] + sh[k], 0.f);
      acc[k] += f * w;
    }
  }
  #pragma unroll
  for (int k = 0; k < 8; ++k) {
    if constexpr (NPW == 4) acc[k] += __shfl_xor(acc[k], 16);
    acc[k] += __shfl_xor(acc[k], 32);
  }
  if (grp == 0) {
    float iv = inv[node];
    bf16x8 o;
    #pragma unroll
    for (int k = 0; k < 8; ++k) o[k] = (short)f2bf(acc[k] * iv);
    *(bf16x8*)(mean + (size_t)node * DIM + sub * 8) = o;
  }
}

// ======================= GEMM building blocks =======================
template <int DIN>
__device__ __forceinline__ void stage_w(const ushort* __restrict__ Wsrc, char* Wt) {
  constexpr int LOGR = (DIN == 256) ? 9 : 8;
  const char* g = (const char*)Wsrc;
  #pragma unroll
  for (int i = 0; i < (64 * DIN * 2) / 4096; ++i) {
    int p = i * 4096 + threadIdx.x * 16;
    int row = p >> LOGR;
    bf16x8 v = *(const bf16x8*)(g + p);
    *(bf16x8*)(Wt + (p ^ ((row & 7) << 4))) = v;
  }
}

// write a register-held W tile into LDS (swizzled); no global loads
template <int DIN>
__device__ __forceinline__ void stage_w_reg(const bf16x8* wr, char* Wt) {
  constexpr int LOGR = (DIN == 256) ? 9 : 8;
  #pragma unroll
  for (int i = 0; i < (64 * DIN * 2) / 4096; ++i) {
    int p = i * 4096 + threadIdx.x * 16;
    int row = p >> LOGR;
    *(bf16x8*)(Wt + (p ^ ((row & 7) << 4))) = wr[i];
  }
}

template <bool AF32, bool BN, int DIN>
__device__ __forceinline__ void load_a(const void* __restrict__ A,
                                       const float* __restrict__ bnp,
                                       int arow, int lb, bf16x8* af) {
  #pragma unroll
  for (int kk = 0; kk < DIN / 32; ++kk) {
    if constexpr (AF32) {
      const float* ap = (const float*)A + (size_t)arow * DIN + kk * 32 + lb * 8;
      float4 u = *(const float4*)ap;
      float4 v = *(const float4*)(ap + 4);
      bf16x8 a;
      a[0] = (short)f2bf(u.x); a[1] = (short)f2bf(u.y);
      a[2] = (short)f2bf(u.z); a[3] = (short)f2bf(u.w);
      a[4] = (short)f2bf(v.x); a[5] = (short)f2bf(v.y);
      a[6] = (short)f2bf(v.z); a[7] = (short)f2bf(v.w);
      af[kk] = a;
    } else {
      bf16x8 r = *(const bf16x8*)((const ushort*)A + (size_t)arow * DIN + kk * 32 + lb * 8);
      if constexpr (BN) {
        int c0 = kk * 32 + lb * 8;
        float4 s0 = *(const float4*)(bnp + c0);
        float4 s1 = *(const float4*)(bnp + c0 + 4);
        float4 h0 = *(const float4*)(bnp + 256 + c0);
        float4 h1 = *(const float4*)(bnp + 256 + c0 + 4);
        r[0] = (short)f2bf(fmaxf(bf2f((ushort)r[0]) * s0.x + h0.x, 0.f));
        r[1] = (short)f2bf(fmaxf(bf2f((ushort)r[1]) * s0.y + h0.y, 0.f));
        r[2] = (short)f2bf(fmaxf(bf2f((ushort)r[2]) * s0.z + h0.z, 0.f));
        r[3] = (short)f2bf(fmaxf(bf2f((ushort)r[3]) * s0.w + h0.w, 0.f));
        r[4] = (short)f2bf(fmaxf(bf2f((ushort)r[4]) * s1.x + h1.x, 0.f));
        r[5] = (short)f2bf(fmaxf(bf2f((ushort)r[5]) * s1.y + h1.y, 0.f));
        r[6] = (short)f2bf(fmaxf(bf2f((ushort)r[6]) * s1.z + h1.z, 0.f));
        r[7] = (short)f2bf(fmaxf(bf2f((ushort)r[7]) * s1.w + h1.w, 0.f));
      }
      af[kk] = r;
    }
  }
}

template <int DIN>
__device__ __forceinline__ void compute(const bf16x8* af, const char* Wt,
                                        int la, int lb, f32x4* acc) {
  constexpr int LOGR = (DIN == 256) ? 9 : 8;
  #pragma unroll
  for (int kk = 0; kk < DIN / 32; ++kk) {
    #pragma unroll
    for (int nf = 0; nf < 4; ++nf) {
      int r = nf * 16 + la;
      int ad = (r << LOGR) + (kk * 32 + lb * 8) * 2;
      ad ^= ((r & 7) << 4);
      bf16x8 b = *(const bf16x8*)(Wt + ad);
      acc[nf] = __builtin_amdgcn_mfma_f32_16x16x32_bf16(af[kk], b, acc[nf], 0, 0, 0);
    }
  }
}

// 1D grid GY*NTILES, XCD-chunked. Dual-256 path (WREG): W2 tile + A2 frags
// issued to REGISTERS after W1's staging loads; the pre-barrier drain absorbs
// their latency under phase-1's; phase 2 is ds_write-from-regs + MFMA only.
template <bool AF32, bool CF32, int DIN, int DOUT, bool DUAL, bool BNA2, bool STATS,
          bool SAMEW, int GY>
__global__ __launch_bounds__(256) void k_gemm(
    const void* __restrict__ A1v, const ushort* __restrict__ W1,
    const void* __restrict__ A2v, const ushort* __restrict__ W2,
    const float* __restrict__ bias, const float* __restrict__ bnp,
    float* __restrict__ stats, void* __restrict__ Cv, int Mstore)
{
  constexpr bool BOTHW = DUAL && !SAMEW && (DIN == 128);
  constexpr bool WREG  = DUAL && !SAMEW && (DIN == 256);
  constexpr int WTB = 64 * DIN * 2;
  constexpr int NSTG = WTB / 4096;
  __shared__ __align__(16) char Wt[(BOTHW ? 2 : 1) * WTB];
  __shared__ float sbuf[64], qbuf[64];

  int orig = xcd_swz<GY * NTILES>(blockIdx.x);
  int bx = orig / GY, by = orig % GY;

  int lane = threadIdx.x & 63, wid = threadIdx.x >> 6;
  int la = lane & 15, lb = lane >> 4;
  int rowBase = bx * 64 + wid * 16;
  int colBase = by * 64;
  int arow = rowBase + la; if (arow >= N_NODES) arow = N_NODES - 1;

  if constexpr (STATS) {
    if (threadIdx.x < 64) { sbuf[threadIdx.x] = 0.f; qbuf[threadIdx.x] = 0.f; }
  }

  f32x4 acc[4];
  #pragma unroll
  for (int i = 0; i < 4; ++i) acc[i] = {0.f, 0.f, 0.f, 0.f};

  bf16x8 af[DIN / 32];
  bf16x8 af2[WREG ? DIN / 32 : 1];
  bf16x8 w2r[WREG ? NSTG : 1];
  load_a<AF32, false, DIN>(A1v, nullptr, arow, lb, af);
  stage_w<DIN>(W1 + (size_t)colBase * DIN, Wt);
  if constexpr (BOTHW) stage_w<DIN>(W2 + (size_t)colBase * DIN, Wt + WTB);
  if constexpr (WREG) {
    // issue AFTER W1 staging loads (queue priority preserved); drained by the
    // barrier below together with W1's -> phase-2 has zero global latency.
    const char* g = (const char*)(W2 + (size_t)colBase * DIN);
    #pragma unroll
    for (int i = 0; i < NSTG; ++i)
      w2r[i] = *(const bf16x8*)(g + i * 4096 + threadIdx.x * 16);
    load_a<false, BNA2, DIN>(A2v, bnp, arow, lb, af2);
  }
  __syncthreads();
  compute<DIN>(af, Wt, la, lb, acc);

  if constexpr (DUAL) {
    if constexpr (BOTHW) {
      load_a<false, BNA2, DIN>(A2v, bnp, arow, lb, af);
      compute<DIN>(af, Wt + WTB, la, lb, acc);
    } else if constexpr (SAMEW) {
      load_a<false, BNA2, DIN>(A2v, bnp, arow, lb, af);
      compute<DIN>(af, Wt, la, lb, acc);
    } else {
      __syncthreads();                    // all waves done reading W1
      stage_w_reg<DIN>(w2r, Wt);          // no global loads
      __syncthreads();
      compute<DIN>(af2, Wt, la, lb, acc);
    }
  }

  // C/D layout: col = lane&15, row = (lane>>4)*4 + reg
  float colsum[4] = {}, colsq[4] = {};
  #pragma unroll
  for (int nf = 0; nf < 4; ++nf) {
    int col = colBase + nf * 16 + la;
    float bv = bias ? bias[col] : 0.0f;
    #pragma unroll
    for (int i = 0; i < 4; ++i) {
      int row = rowBase + lb * 4 + i;
      float o = acc[nf][i] + bv;
      if (row < Mstore) {
        if constexpr (CF32) ((float*)Cv)[(size_t)row * DOUT + col] = o;
        else                ((ushort*)Cv)[(size_t)row * DOUT + col] = f2bf(o);
      }
      if constexpr (STATS) {
        if (row < N_NODES) { colsum[nf] += o; colsq[nf] += o * o; }
      }
    }
  }

  if constexpr (STATS) {
    #pragma unroll
    for (int nf = 0; nf < 4; ++nf) {
      float sv = colsum[nf], qv = colsq[nf];
      sv += __shfl_xor(sv, 16); qv += __shfl_xor(qv, 16);
      sv += __shfl_xor(sv, 32); qv += __shfl_xor(qv, 32);
      if (lb == 0) { atomicAdd(&sbuf[nf * 16 + la], sv); atomicAdd(&qbuf[nf * 16 + la], qv); }
    }
    __syncthreads();
    if (threadIdx.x < 64)        atomicAdd(&stats[colBase + threadIdx.x], sbuf[threadIdx.x]);
    else if (threadIdx.x < 128)  atomicAdd(&stats[256 + colBase + threadIdx.x - 64], qbuf[threadIdx.x - 64]);
  }
}

// --------- layer-3 PQ GEMM: P = BN(z)@Wl^T, Q = BN(z)@Wr^T + bl ---------
// Wr tile prefetched to registers alongside Wl staging (same T14 pattern).
__global__ __launch_bounds__(256) void k_gemm_pq(
    const ushort* __restrict__ z, const ushort* __restrict__ Wl,
    const ushort* __restrict__ Wr, const float* __restrict__ bl,
    const float* __restrict__ bnp, ushort* __restrict__ P, ushort* __restrict__ Q)
{
  constexpr int DIN = 256, DOUT = 128;
  constexpr int NSTG = (64 * DIN * 2) / 4096;
  __shared__ __align__(16) char Wt[64 * DIN * 2];
  int lane = threadIdx.x & 63, wid = threadIdx.x >> 6;
  int la = lane & 15, lb = lane >> 4;
  int rowBase = blockIdx.y * 64 + wid * 16;
  int colBase = blockIdx.x * 64;
  int arow = rowBase + la; if (arow >= N_NODES) arow = N_NODES - 1;

  bf16x8 af[DIN / 32];
  bf16x8 wrr[NSTG];
  load_a<false, true, DIN>(z, bnp, arow, lb, af);
  stage_w<DIN>(Wl + (size_t)colBase * DIN, Wt);
  {
    const char* g = (const char*)(Wr + (size_t)colBase * DIN);
    #pragma unroll
    for (int i = 0; i < NSTG; ++i)
      wrr[i] = *(const bf16x8*)(g + i * 4096 + threadIdx.x * 16);
  }
  __syncthreads();

  f32x4 acc[4];
  #pragma unroll
  for (int i = 0; i < 4; ++i) acc[i] = {0.f, 0.f, 0.f, 0.f};
  compute<DIN>(af, Wt, la, lb, acc);
  #pragma unroll
  for (int nf = 0; nf < 4; ++nf) {
    int col = colBase + nf * 16 + la;
    #pragma unroll
    for (int i = 0; i < 4; ++i) {
      int row = rowBase + lb * 4 + i;
      if (row < N_NODES) P[(size_t)row * DOUT + col] = f2bf(acc[nf][i]);
    }
  }

  __syncthreads();
  stage_w_reg<DIN>(wrr, Wt);
  __syncthreads();
  #pragma unroll
  for (int i = 0; i < 4; ++i) acc[i] = {0.f, 0.f, 0.f, 0.f};
  compute<DIN>(af, Wt, la, lb, acc);
  #pragma unroll
  for (int nf = 0; nf < 4; ++nf) {
    int col = colBase + nf * 16 + la;
    float bv = bl[col];
    #pragma unroll
    for (int i = 0; i < 4; ++i) {
      int row = rowBase + lb * 4 + i;
      if (row < N_NODES) Q[(size_t)row * DOUT + col] = f2bf(acc[nf][i] + bv);
    }
  }
}

// ---------- per-column BN scale/shift ----------
__global__ void k_bnprep(const float* __restrict__ stats, const float* __restrict__ gamma,
                         const float* __restrict__ beta, float* __restrict__ bnp) {
  int c = threadIdx.x;
  float m = stats[c] * (1.0f / N_NODES);
  float var = stats[256 + c] * (1.0f / N_NODES) - m * m;
  float rs = rsqrtf(var + BN_EPS);
  float sc = rs * gamma[c];
  bnp[c] = sc;
  bnp[256 + c] = beta[c] - m * sc;
}

extern "C" void kernel_launch(void* const* d_in, const int* in_sizes, int n_in,
                              void* d_out, int out_size, void* d_ws, size_t ws_size,
                              hipStream_t stream) {
  const float* x    = (const float*)d_in[0];
  const int*   ei   = (const int*)d_in[1];
  const float* encW = (const float*)d_in[2];
  const float* encb = (const float*)d_in[3];
  const float* Wl0  = (const float*)d_in[4];
  const float* bl0  = (const float*)d_in[5];
  const float* Wr0  = (const float*)d_in[6];
  const float* Wl1  = (const float*)d_in[7];
  const float* bl1  = (const float*)d_in[8];
  const float* Wr1  = (const float*)d_in[9];
  const float* Wl2  = (const float*)d_in[10];
  const float* bl2  = (const float*)d_in[11];
  const float* Wr2  = (const float*)d_in[12];
  const float* Wl3  = (const float*)d_in[13];
  const float* bl3  = (const float*)d_in[14];
  const float* Wr3  = (const float*)d_in[15];
  const float* g0   = (const float*)d_in[16];
  const float* b0   = (const float*)d_in[17];
  const float* g1   = (const float*)d_in[18];
  const float* b1   = (const float*)d_in[19];
  const float* g2   = (const float*)d_in[20];
  const float* b2   = (const float*)d_in[21];
  const float* decW = (const float*)d_in[22];
  const float* decb = (const float*)d_in[23];

  const int* src = ei;
  const int* dst = ei + N_EDGES;

  char* ws = (char*)d_ws;
  size_t off = 0;
  auto alloc = [&](size_t bytes) { char* p = ws + off; off += (bytes + 255) & ~255ull; return p; };
  ushort* bufA   = (ushort*)alloc((size_t)NPAD * 256 * 2);
  ushort* bufB   = (ushort*)alloc((size_t)NPAD * 256 * 2);
  ushort* mean   = (ushort*)alloc((size_t)NPAD * 256 * 2);
  int*    deg    = (int*)   alloc((size_t)N_NODES * 4);    // deg + stats adjacent:
  float*  stats  = (float*) alloc(3 * 512 * 4);            // single memset covers both
  int*    part   = (int*)   alloc((size_t)N_NODES * 4);
  int*    bsum   = (int*)   alloc(128 * 4);
  int*    rowptr = (int*)   alloc((size_t)(N_NODES + 1) * 4);
  int*    cursor = (int*)   alloc((size_t)N_NODES * 4);
  int*    colidx = (int*)   alloc((size_t)N_EDGES * 4);
  float*  inv    = (float*) alloc((size_t)N_NODES * 4);
  float*  bnp    = (float*) alloc(3 * 512 * 4);
  ushort* wpool  = (ushort*)alloc(425984 * 2);

  float* stats0 = stats, *stats1 = stats + 512, *stats2 = stats + 1024;
  float* bnp0 = bnp, *bnp1 = bnp + 512, *bnp2 = bnp + 1024;

  const ushort* wEnc = wpool;
  const ushort* wL0  = wpool + 16384;
  const ushort* wR0  = wpool + 49152;
  const ushort* wL1  = wpool + 81920;
  const ushort* wR1  = wpool + 147456;
  const ushort* wL2  = wpool + 212992;
  const ushort* wR2  = wpool + 278528;
  const ushort* wL3  = wpool + 344064;
  const ushort* wR3  = wpool + 376832;
  const ushort* wDec = wpool + 409600;

  // ---- CSR build + weight convert (deg & stats zeroed in one memset) ----
  size_t degPad = ((size_t)N_NODES * 4 + 255) & ~255ull;
  hipMemsetAsync(deg, 0, degPad + 3 * 512 * 4, stream);
  k_prep<<<CVTB + (N_EDGES + 255) / 256, 256, 0, stream>>>(
      encW, Wl0, Wr0, Wl1, Wr1, Wl2, Wr2, Wl3, Wr3, decW, wpool, dst, deg);
  k_scanA<<<NBLK, 256, 0, stream>>>(deg, part, bsum);
  k_scanC<<<NBLK, 256, 0, stream>>>(deg, part, bsum, rowptr, cursor, inv);
  k_fill<<<(N_EDGES + 255) / 256, 256, 0, stream>>>(src, dst, cursor, colidx);

  const int GGRID = NTILES;   // 313
  const int NGB = (N_NODES + 3) / 4;

  // encoder: e(bufA) = x @ encW^T + encb  (f32 A, bf16 C)
  k_gemm<true, false, 128, 128, false, false, false, false, 2>
      <<<2 * GGRID, 256, 0, stream>>>(
      x, wEnc, nullptr, nullptr, encb, nullptr, nullptr, bufA, N_NODES);

  // SAGE0: h0(bufB) = mean(e)@Wl0 + bl0 + e@Wr0 ; stats0  (BOTHW)
  k_gather<128, false><<<NGB, 256, 0, stream>>>(bufA, rowptr, colidx, inv, nullptr, mean);
  k_gemm<false, false, 128, 256, true, false, true, false, 4>
      <<<4 * GGRID, 256, 0, stream>>>(
      mean, wL0, bufA, wR0, bl0, nullptr, stats0, bufB, N_NODES);
  k_bnprep<<<1, 256, 0, stream>>>(stats0, g0, b0, bnp0);

  // SAGE1: z1 = BN0(h0); h1(bufA) ; stats1  (WREG)
  k_gather<256, true><<<NGB, 256, 0, stream>>>(bufB, rowptr, colidx, inv, bnp0, mean);
  k_gemm<false, false, 256, 256, true, true, true, false, 4>
      <<<4 * GGRID, 256, 0, stream>>>(
      mean, wL1, bufB, wR1, bl1, bnp0, stats1, bufA, N_NODES);
  k_bnprep<<<1, 256, 0, stream>>>(stats1, g1, b1, bnp1);

  // SAGE2: h2(bufB) ; stats2  (WREG)
  k_gather<256, true><<<NGB, 256, 0, stream>>>(bufA, rowptr, colidx, inv, bnp1, mean);
  k_gemm<false, false, 256, 256, true, true, true, false, 4>
      <<<4 * GGRID, 256, 0, stream>>>(
      mean, wL2, bufA, wR2, bl2, bnp1, stats2, bufB, N_NODES);
  k_bnprep<<<1, 256, 0, stream>>>(stats2, g2, b2, bnp2);

  // SAGE3 re-associated: P = z3@Wl3^T, Q = z3@Wr3^T + bl3  (z3 = BN2(h2))
  ushort* P = mean;                          // NPAD x 128
  ushort* Q = mean + (size_t)NPAD * 128;     // NPAD x 128
  k_gemm_pq<<<dim3(2, GGRID), 256, 0, stream>>>(bufB, wL3, wR3, bl3, bnp2, P, Q);

  // meanP(bufA) = gather-mean of P (128-dim)
  k_gather<128, false><<<NGB, 256, 0, stream>>>(P, rowptr, colidx, inv, nullptr, bufA);

  // decoder: d_out = (meanP + Q) @ decW^T + decb  (same-W dual, f32 out)
  k_gemm<false, true, 128, 128, true, false, false, true, 2>
      <<<2 * GGRID, 256, 0, stream>>>(
      bufA, wDec, Q, nullptr, decb, nullptr, nullptr, (float*)d_out, N_NODES);
}

// Round 19
// 229.632 us; speedup vs baseline: 1.0729x; 1.0729x over previous
//
#include <hip/hip_runtime.h>

#define N_NODES 20000
#define N_EDGES 320000
#define NPAD    20032
#define NTILES  313         // NPAD/64
#define BN_EPS  1e-5f
#define NBLK    79          // ceil(20000/256)
#define CVTB    416         // 106496 threads / 256 for weight conversion

using bf16x8 = __attribute__((ext_vector_type(8))) short;
using f32x4  = __attribute__((ext_vector_type(4))) float;

__device__ __forceinline__ float bf2f(ushort u) {
  union { unsigned i; float f; } t; t.i = ((unsigned)u) << 16; return t.f;
}
__device__ __forceinline__ ushort f2bf(float f) {
  unsigned x = __float_as_uint(f);
  return (ushort)((x + 0x7fffu + ((x >> 16) & 1u)) >> 16);   // RNE
}

// bijective XCD-chunked swizzle (m204)
template <int NWG>
__device__ __forceinline__ int xcd_swz(int bid) {
  constexpr int Q = NWG / 8, R = NWG % 8;
  int xcd = bid & 7, pos = bid >> 3;
  return (xcd < R) ? (xcd * (Q + 1) + pos) : (R * (Q + 1) + (xcd - R) * Q + pos);
}

// ---------- fused: weights -> bf16 pool  +  degree count ----------
__global__ void k_prep(const float* s0, const float* s1, const float* s2,
                       const float* s3, const float* s4, const float* s5,
                       const float* s6, const float* s7, const float* s8,
                       const float* s9, ushort* __restrict__ wdst,
                       const int* __restrict__ edst, int* __restrict__ deg) {
  int b = blockIdx.x;
  if (b < CVTB) {
    int e = (b * 256 + threadIdx.x) * 4;
    if (e >= 425984) return;
    const float* s; int off;
    if      (e < 16384)  { s = s0; off = e; }
    else if (e < 49152)  { s = s1; off = e - 16384; }
    else if (e < 81920)  { s = s2; off = e - 49152; }
    else if (e < 147456) { s = s3; off = e - 81920; }
    else if (e < 212992) { s = s4; off = e - 147456; }
    else if (e < 278528) { s = s5; off = e - 212992; }
    else if (e < 344064) { s = s6; off = e - 278528; }
    else if (e < 376832) { s = s7; off = e - 344064; }
    else if (e < 409600) { s = s8; off = e - 376832; }
    else                 { s = s9; off = e - 409600; }
    float4 v = *(const float4*)(s + off);
    wdst[e + 0] = f2bf(v.x); wdst[e + 1] = f2bf(v.y);
    wdst[e + 2] = f2bf(v.z); wdst[e + 3] = f2bf(v.w);
  } else {
    int t = (b - CVTB) * 256 + threadIdx.x;
    if (t < N_EDGES) {
      unsigned d = (unsigned)edst[t];
      if (d < N_NODES) atomicAdd(&deg[d], 1);
    }
  }
}

// ---------- CSR scan ----------
__global__ void k_scanA(const int* __restrict__ deg, int* __restrict__ part,
                        int* __restrict__ bsum) {
  __shared__ int buf[256];
  int i = blockIdx.x * 256 + threadIdx.x;
  int v = (i < N_NODES) ? deg[i] : 0;
  buf[threadIdx.x] = v;
  __syncthreads();
  #pragma unroll
  for (int s = 1; s < 256; s <<= 1) {
    int t = (threadIdx.x >= s) ? buf[threadIdx.x - s] : 0;
    __syncthreads();
    buf[threadIdx.x] += t;
    __syncthreads();
  }
  if (i < N_NODES) part[i] = buf[threadIdx.x];
  if (threadIdx.x == 255) bsum[blockIdx.x] = buf[255];
}

__global__ void k_scanC(const int* __restrict__ deg, const int* __restrict__ part,
                        const int* __restrict__ bsum, int* __restrict__ rowptr,
                        int* __restrict__ cursor, float* __restrict__ inv) {
  __shared__ int soff;
  if (threadIdx.x == 0) {
    int o = 0;
    for (int b = 0; b < blockIdx.x; ++b) o += bsum[b];
    soff = o;
  }
  __syncthreads();
  int i = blockIdx.x * 256 + threadIdx.x;
  if (i >= N_NODES) return;
  int r1 = soff + part[i];
  int d = deg[i];
  rowptr[i + 1] = r1;
  cursor[i] = r1 - d;
  if (i == 0) rowptr[0] = 0;
  inv[i] = 1.0f / (float)max(d, 1);
}

__global__ void k_fill(const int* __restrict__ src, const int* __restrict__ dst,
                       int* __restrict__ cursor, int* __restrict__ col) {
  int e = blockIdx.x * blockDim.x + threadIdx.x;
  if (e >= N_EDGES) return;
  unsigned d = (unsigned)dst[e];
  if (d >= N_NODES) return;
  int p = atomicAdd(&cursor[d], 1);
  col[p] = src[e];
}

// ---------- gather-mean; BN scale/shift computed in-register from raw stats ----------
template <int DIM, bool BN>
__global__ __launch_bounds__(256) void k_gather(
    const ushort* __restrict__ z, const int* __restrict__ rowptr,
    const int* __restrict__ col, const float* __restrict__ inv,
    const float* __restrict__ stats, const float* __restrict__ gamma,
    const float* __restrict__ beta, ushort* __restrict__ mean) {
  constexpr int LPR = DIM / 8;
  constexpr int NPW = 64 / LPR;
  int node = blockIdx.x * 4 + (threadIdx.x >> 6);
  if (node >= N_NODES) return;
  int lane = threadIdx.x & 63;
  int grp = lane / LPR;
  int sub = lane % LPR;
  float sc[8], sh[8];
  if constexpr (BN) {
    #pragma unroll
    for (int k = 0; k < 8; ++k) {
      int c = sub * 8 + k;
      float m = stats[c] * (1.0f / N_NODES);
      float var = stats[256 + c] * (1.0f / N_NODES) - m * m;
      float rs = rsqrtf(var + BN_EPS);
      sc[k] = rs * gamma[c];
      sh[k] = beta[c] - m * sc[k];
    }
  }
  float acc[8] = {};
  int r0 = rowptr[node], r1 = rowptr[node + 1];
  #pragma unroll 2
  for (int j = r0; j < r1; j += NPW) {
    int jj = j + grp;
    bool val = jj < r1;
    int nb = val ? col[jj] : 0;
    bf16x8 v = *(const bf16x8*)(z + (size_t)nb * DIM + sub * 8);
    float w = val ? 1.f : 0.f;
    #pragma unroll
    for (int k = 0; k < 8; ++k) {
      float f = bf2f((ushort)v[k]);
      if constexpr (BN) f = fmaxf(f * sc[k] + sh[k], 0.f);
      acc[k] += f * w;
    }
  }
  #pragma unroll
  for (int k = 0; k < 8; ++k) {
    if constexpr (NPW == 4) acc[k] += __shfl_xor(acc[k], 16);
    acc[k] += __shfl_xor(acc[k], 32);
  }
  if (grp == 0) {
    float iv = inv[node];
    bf16x8 o;
    #pragma unroll
    for (int k = 0; k < 8; ++k) o[k] = (short)f2bf(acc[k] * iv);
    *(bf16x8*)(mean + (size_t)node * DIM + sub * 8) = o;
  }
}

// ======================= GEMM building blocks =======================
template <int DIN>
__device__ __forceinline__ void stage_w(const ushort* __restrict__ Wsrc, char* Wt) {
  constexpr int LOGR = (DIN == 256) ? 9 : 8;
  const char* g = (const char*)Wsrc;
  #pragma unroll
  for (int i = 0; i < (64 * DIN * 2) / 4096; ++i) {
    int p = i * 4096 + threadIdx.x * 16;
    int row = p >> LOGR;
    bf16x8 v = *(const bf16x8*)(g + p);
    *(bf16x8*)(Wt + (p ^ ((row & 7) << 4))) = v;
  }
}

// raw A-fragment load (no BN)
template <bool AF32, int DIN>
__device__ __forceinline__ void load_a(const void* __restrict__ A,
                                       int arow, int lb, bf16x8* af) {
  #pragma unroll
  for (int kk = 0; kk < DIN / 32; ++kk) {
    if constexpr (AF32) {
      const float* ap = (const float*)A + (size_t)arow * DIN + kk * 32 + lb * 8;
      float4 u = *(const float4*)ap;
      float4 v = *(const float4*)(ap + 4);
      bf16x8 a;
      a[0] = (short)f2bf(u.x); a[1] = (short)f2bf(u.y);
      a[2] = (short)f2bf(u.z); a[3] = (short)f2bf(u.w);
      a[4] = (short)f2bf(v.x); a[5] = (short)f2bf(v.y);
      a[6] = (short)f2bf(v.z); a[7] = (short)f2bf(v.w);
      af[kk] = a;
    } else {
      af[kk] = *(const bf16x8*)((const ushort*)A + (size_t)arow * DIN + kk * 32 + lb * 8);
    }
  }
}

// apply BN affine+ReLU to fragments from a (LDS) table bnp[512]
template <int DIN>
__device__ __forceinline__ void apply_bn(bf16x8* af, const float* bnp, int lb) {
  #pragma unroll
  for (int kk = 0; kk < DIN / 32; ++kk) {
    int c0 = kk * 32 + lb * 8;
    float4 s0 = *(const float4*)(bnp + c0);
    float4 s1 = *(const float4*)(bnp + c0 + 4);
    float4 h0 = *(const float4*)(bnp + 256 + c0);
    float4 h1 = *(const float4*)(bnp + 256 + c0 + 4);
    bf16x8 r = af[kk];
    r[0] = (short)f2bf(fmaxf(bf2f((ushort)r[0]) * s0.x + h0.x, 0.f));
    r[1] = (short)f2bf(fmaxf(bf2f((ushort)r[1]) * s0.y + h0.y, 0.f));
    r[2] = (short)f2bf(fmaxf(bf2f((ushort)r[2]) * s0.z + h0.z, 0.f));
    r[3] = (short)f2bf(fmaxf(bf2f((ushort)r[3]) * s0.w + h0.w, 0.f));
    r[4] = (short)f2bf(fmaxf(bf2f((ushort)r[4]) * s1.x + h1.x, 0.f));
    r[5] = (short)f2bf(fmaxf(bf2f((ushort)r[5]) * s1.y + h1.y, 0.f));
    r[6] = (short)f2bf(fmaxf(bf2f((ushort)r[6]) * s1.z + h1.z, 0.f));
    r[7] = (short)f2bf(fmaxf(bf2f((ushort)r[7]) * s1.w + h1.w, 0.f));
    af[kk] = r;
  }
}

// compute bnp[512] in LDS from raw stats (one channel per thread)
__device__ __forceinline__ void prep_bn_lds(const float* __restrict__ stats,
                                            const float* __restrict__ gamma,
                                            const float* __restrict__ beta,
                                            float* bnps) {
  int c = threadIdx.x;            // 256 threads = 256 channels
  float m = stats[c] * (1.0f / N_NODES);
  float var = stats[256 + c] * (1.0f / N_NODES) - m * m;
  float rs = rsqrtf(var + BN_EPS);
  float scv = rs * gamma[c];
  bnps[c] = scv;
  bnps[256 + c] = beta[c] - m * scv;
}

template <int DIN>
__device__ __forceinline__ void compute(const bf16x8* af, const char* Wt,
                                        int la, int lb, f32x4* acc) {
  constexpr int LOGR = (DIN == 256) ? 9 : 8;
  #pragma unroll
  for (int kk = 0; kk < DIN / 32; ++kk) {
    #pragma unroll
    for (int nf = 0; nf < 4; ++nf) {
      int r = nf * 16 + la;
      int ad = (r << LOGR) + (kk * 32 + lb * 8) * 2;
      ad ^= ((r & 7) << 4);
      bf16x8 b = *(const bf16x8*)(Wt + ad);
      acc[nf] = __builtin_amdgcn_mfma_f32_16x16x32_bf16(af[kk], b, acc[nf], 0, 0, 0);
    }
  }
}

// 1D grid GY*NTILES, XCD-chunked. Round-17 two-phase schedule; BOTHW for
// DIN==128 distinct-W duals. BNA2: BN table built in LDS pre-barrier.
template <bool AF32, bool CF32, int DIN, int DOUT, bool DUAL, bool BNA2, bool STATS,
          bool SAMEW, int GY>
__global__ __launch_bounds__(256) void k_gemm(
    const void* __restrict__ A1v, const ushort* __restrict__ W1,
    const void* __restrict__ A2v, const ushort* __restrict__ W2,
    const float* __restrict__ bias, const float* __restrict__ bnstats,
    const float* __restrict__ gamma, const float* __restrict__ beta,
    float* __restrict__ stats, void* __restrict__ Cv, int Mstore)
{
  constexpr bool BOTHW = DUAL && !SAMEW && (DIN == 128);
  constexpr int WTB = 64 * DIN * 2;
  __shared__ __align__(16) char Wt[(BOTHW ? 2 : 1) * WTB];
  __shared__ float sbuf[64], qbuf[64];
  __shared__ float bnps[BNA2 ? 512 : 4];

  int orig = xcd_swz<GY * NTILES>(blockIdx.x);
  int bx = orig / GY, by = orig % GY;

  int lane = threadIdx.x & 63, wid = threadIdx.x >> 6;
  int la = lane & 15, lb = lane >> 4;
  int rowBase = bx * 64 + wid * 16;
  int colBase = by * 64;
  int arow = rowBase + la; if (arow >= N_NODES) arow = N_NODES - 1;

  if constexpr (STATS) {
    if (threadIdx.x < 64) { sbuf[threadIdx.x] = 0.f; qbuf[threadIdx.x] = 0.f; }
  }
  if constexpr (BNA2) prep_bn_lds(bnstats, gamma, beta, bnps);

  f32x4 acc[4];
  #pragma unroll
  for (int i = 0; i < 4; ++i) acc[i] = {0.f, 0.f, 0.f, 0.f};

  bf16x8 af[DIN / 32];
  load_a<AF32, DIN>(A1v, arow, lb, af);
  stage_w<DIN>(W1 + (size_t)colBase * DIN, Wt);
  if constexpr (BOTHW) stage_w<DIN>(W2 + (size_t)colBase * DIN, Wt + WTB);
  __syncthreads();
  compute<DIN>(af, Wt, la, lb, acc);

  if constexpr (DUAL) {
    if constexpr (BOTHW) {
      load_a<false, DIN>(A2v, arow, lb, af);
      if constexpr (BNA2) apply_bn<DIN>(af, bnps, lb);
      compute<DIN>(af, Wt + WTB, la, lb, acc);
    } else if constexpr (SAMEW) {
      load_a<false, DIN>(A2v, arow, lb, af);
      if constexpr (BNA2) apply_bn<DIN>(af, bnps, lb);
      compute<DIN>(af, Wt, la, lb, acc);
    } else {
      __syncthreads();
      load_a<false, DIN>(A2v, arow, lb, af);
      stage_w<DIN>(W2 + (size_t)colBase * DIN, Wt);
      if constexpr (BNA2) apply_bn<DIN>(af, bnps, lb);
      __syncthreads();
      compute<DIN>(af, Wt, la, lb, acc);
    }
  }

  // C/D layout: col = lane&15, row = (lane>>4)*4 + reg
  float colsum[4] = {}, colsq[4] = {};
  #pragma unroll
  for (int nf = 0; nf < 4; ++nf) {
    int col = colBase + nf * 16 + la;
    float bv = bias ? bias[col] : 0.0f;
    #pragma unroll
    for (int i = 0; i < 4; ++i) {
      int row = rowBase + lb * 4 + i;
      float o = acc[nf][i] + bv;
      if (row < Mstore) {
        if constexpr (CF32) ((float*)Cv)[(size_t)row * DOUT + col] = o;
        else                ((ushort*)Cv)[(size_t)row * DOUT + col] = f2bf(o);
      }
      if constexpr (STATS) {
        if (row < N_NODES) { colsum[nf] += o; colsq[nf] += o * o; }
      }
    }
  }

  if constexpr (STATS) {
    #pragma unroll
    for (int nf = 0; nf < 4; ++nf) {
      float sv = colsum[nf], qv = colsq[nf];
      sv += __shfl_xor(sv, 16); qv += __shfl_xor(qv, 16);
      sv += __shfl_xor(sv, 32); qv += __shfl_xor(qv, 32);
      if (lb == 0) { atomicAdd(&sbuf[nf * 16 + la], sv); atomicAdd(&qbuf[nf * 16 + la], qv); }
    }
    __syncthreads();
    if (threadIdx.x < 64)        atomicAdd(&stats[colBase + threadIdx.x], sbuf[threadIdx.x]);
    else if (threadIdx.x < 128)  atomicAdd(&stats[256 + colBase + threadIdx.x - 64], qbuf[threadIdx.x - 64]);
  }
}

// --------- layer-3 PQ GEMM: P = BN(z)@Wl^T, Q = BN(z)@Wr^T + bl ---------
__global__ __launch_bounds__(256) void k_gemm_pq(
    const ushort* __restrict__ z, const ushort* __restrict__ Wl,
    const ushort* __restrict__ Wr, const float* __restrict__ bl,
    const float* __restrict__ bnstats, const float* __restrict__ gamma,
    const float* __restrict__ beta, ushort* __restrict__ P, ushort* __restrict__ Q)
{
  constexpr int DIN = 256, DOUT = 128;
  __shared__ __align__(16) char Wt[64 * DIN * 2];
  __shared__ float bnps[512];
  int lane = threadIdx.x & 63, wid = threadIdx.x >> 6;
  int la = lane & 15, lb = lane >> 4;
  int rowBase = blockIdx.y * 64 + wid * 16;
  int colBase = blockIdx.x * 64;
  int arow = rowBase + la; if (arow >= N_NODES) arow = N_NODES - 1;

  prep_bn_lds(bnstats, gamma, beta, bnps);

  bf16x8 af[DIN / 32];
  load_a<false, DIN>(z, arow, lb, af);            // raw; BN applied post-barrier
  stage_w<DIN>(Wl + (size_t)colBase * DIN, Wt);
  __syncthreads();
  apply_bn<DIN>(af, bnps, lb);

  f32x4 acc[4];
  #pragma unroll
  for (int i = 0; i < 4; ++i) acc[i] = {0.f, 0.f, 0.f, 0.f};
  compute<DIN>(af, Wt, la, lb, acc);
  #pragma unroll
  for (int nf = 0; nf < 4; ++nf) {
    int col = colBase + nf * 16 + la;
    #pragma unroll
    for (int i = 0; i < 4; ++i) {
      int row = rowBase + lb * 4 + i;
      if (row < N_NODES) P[(size_t)row * DOUT + col] = f2bf(acc[nf][i]);
    }
  }

  __syncthreads();
  stage_w<DIN>(Wr + (size_t)colBase * DIN, Wt);
  __syncthreads();
  #pragma unroll
  for (int i = 0; i < 4; ++i) acc[i] = {0.f, 0.f, 0.f, 0.f};
  compute<DIN>(af, Wt, la, lb, acc);
  #pragma unroll
  for (int nf = 0; nf < 4; ++nf) {
    int col = colBase + nf * 16 + la;
    float bv = bl[col];
    #pragma unroll
    for (int i = 0; i < 4; ++i) {
      int row = rowBase + lb * 4 + i;
      if (row < N_NODES) Q[(size_t)row * DOUT + col] = f2bf(acc[nf][i] + bv);
    }
  }
}

extern "C" void kernel_launch(void* const* d_in, const int* in_sizes, int n_in,
                              void* d_out, int out_size, void* d_ws, size_t ws_size,
                              hipStream_t stream) {
  const float* x    = (const float*)d_in[0];
  const int*   ei   = (const int*)d_in[1];
  const float* encW = (const float*)d_in[2];
  const float* encb = (const float*)d_in[3];
  const float* Wl0  = (const float*)d_in[4];
  const float* bl0  = (const float*)d_in[5];
  const float* Wr0  = (const float*)d_in[6];
  const float* Wl1  = (const float*)d_in[7];
  const float* bl1  = (const float*)d_in[8];
  const float* Wr1  = (const float*)d_in[9];
  const float* Wl2  = (const float*)d_in[10];
  const float* bl2  = (const float*)d_in[11];
  const float* Wr2  = (const float*)d_in[12];
  const float* Wl3  = (const float*)d_in[13];
  const float* bl3  = (const float*)d_in[14];
  const float* Wr3  = (const float*)d_in[15];
  const float* g0   = (const float*)d_in[16];
  const float* b0   = (const float*)d_in[17];
  const float* g1   = (const float*)d_in[18];
  const float* b1   = (const float*)d_in[19];
  const float* g2   = (const float*)d_in[20];
  const float* b2   = (const float*)d_in[21];
  const float* decW = (const float*)d_in[22];
  const float* decb = (const float*)d_in[23];

  const int* src = ei;
  const int* dst = ei + N_EDGES;

  char* ws = (char*)d_ws;
  size_t off = 0;
  auto alloc = [&](size_t bytes) { char* p = ws + off; off += (bytes + 255) & ~255ull; return p; };
  ushort* bufA   = (ushort*)alloc((size_t)NPAD * 256 * 2);
  ushort* bufB   = (ushort*)alloc((size_t)NPAD * 256 * 2);
  ushort* mean   = (ushort*)alloc((size_t)NPAD * 256 * 2);
  int*    deg    = (int*)   alloc((size_t)N_NODES * 4);    // deg + stats adjacent:
  float*  stats  = (float*) alloc(3 * 512 * 4);            // single memset covers both
  int*    part   = (int*)   alloc((size_t)N_NODES * 4);
  int*    bsum   = (int*)   alloc(128 * 4);
  int*    rowptr = (int*)   alloc((size_t)(N_NODES + 1) * 4);
  int*    cursor = (int*)   alloc((size_t)N_NODES * 4);
  int*    colidx = (int*)   alloc((size_t)N_EDGES * 4);
  float*  inv    = (float*) alloc((size_t)N_NODES * 4);
  ushort* wpool  = (ushort*)alloc(425984 * 2);

  float* stats0 = stats, *stats1 = stats + 512, *stats2 = stats + 1024;

  const ushort* wEnc = wpool;
  const ushort* wL0  = wpool + 16384;
  const ushort* wR0  = wpool + 49152;
  const ushort* wL1  = wpool + 81920;
  const ushort* wR1  = wpool + 147456;
  const ushort* wL2  = wpool + 212992;
  const ushort* wR2  = wpool + 278528;
  const ushort* wL3  = wpool + 344064;
  const ushort* wR3  = wpool + 376832;
  const ushort* wDec = wpool + 409600;

  // ---- CSR build + weight convert (deg & stats zeroed in one memset) ----
  size_t degPad = ((size_t)N_NODES * 4 + 255) & ~255ull;
  hipMemsetAsync(deg, 0, degPad + 3 * 512 * 4, stream);
  k_prep<<<CVTB + (N_EDGES + 255) / 256, 256, 0, stream>>>(
      encW, Wl0, Wr0, Wl1, Wr1, Wl2, Wr2, Wl3, Wr3, decW, wpool, dst, deg);
  k_scanA<<<NBLK, 256, 0, stream>>>(deg, part, bsum);
  k_scanC<<<NBLK, 256, 0, stream>>>(deg, part, bsum, rowptr, cursor, inv);
  k_fill<<<(N_EDGES + 255) / 256, 256, 0, stream>>>(src, dst, cursor, colidx);

  const int GGRID = NTILES;   // 313
  const int NGB = (N_NODES + 3) / 4;

  // encoder: e(bufA) = x @ encW^T + encb  (f32 A, bf16 C)
  k_gemm<true, false, 128, 128, false, false, false, false, 2>
      <<<2 * GGRID, 256, 0, stream>>>(
      x, wEnc, nullptr, nullptr, encb, nullptr, nullptr, nullptr, nullptr,
      bufA, N_NODES);

  // SAGE0: h0(bufB) = mean(e)@Wl0 + bl0 + e@Wr0 ; stats0  (BOTHW)
  k_gather<128, false><<<NGB, 256, 0, stream>>>(
      bufA, rowptr, colidx, inv, nullptr, nullptr, nullptr, mean);
  k_gemm<false, false, 128, 256, true, false, true, false, 4>
      <<<4 * GGRID, 256, 0, stream>>>(
      mean, wL0, bufA, wR0, bl0, nullptr, nullptr, nullptr, stats0, bufB, N_NODES);

  // SAGE1: z1 = BN0(h0); h1(bufA) ; stats1
  k_gather<256, true><<<NGB, 256, 0, stream>>>(
      bufB, rowptr, colidx, inv, stats0, g0, b0, mean);
  k_gemm<false, false, 256, 256, true, true, true, false, 4>
      <<<4 * GGRID, 256, 0, stream>>>(
      mean, wL1, bufB, wR1, bl1, stats0, g0, b0, stats1, bufA, N_NODES);

  // SAGE2: h2(bufB) ; stats2
  k_gather<256, true><<<NGB, 256, 0, stream>>>(
      bufA, rowptr, colidx, inv, stats1, g1, b1, mean);
  k_gemm<false, false, 256, 256, true, true, true, false, 4>
      <<<4 * GGRID, 256, 0, stream>>>(
      mean, wL2, bufA, wR2, bl2, stats1, g1, b1, stats2, bufB, N_NODES);

  // SAGE3 re-associated: P = z3@Wl3^T, Q = z3@Wr3^T + bl3  (z3 = BN2(h2))
  ushort* P = mean;                          // NPAD x 128
  ushort* Q = mean + (size_t)NPAD * 128;     // NPAD x 128
  k_gemm_pq<<<dim3(2, GGRID), 256, 0, stream>>>(bufB, wL3, wR3, bl3,
                                                stats2, g2, b2, P, Q);

  // meanP(bufA) = gather-mean of P (128-dim)
  k_gather<128, false><<<NGB, 256, 0, stream>>>(
      P, rowptr, colidx, inv, nullptr, nullptr, nullptr, bufA);

  // decoder: d_out = (meanP + Q) @ decW^T + decb  (same-W dual, f32 out)
  k_gemm<false, true, 128, 128, true, false, false, true, 2>
      <<<2 * GGRID, 256, 0, stream>>>(
      bufA, wDec, Q, nullptr, decb, nullptr, nullptr, nullptr, nullptr,
      (float*)d_out, N_NODES);
}

// Round 20
// 226.913 us; speedup vs baseline: 1.0858x; 1.0120x over previous
//
#include <hip/hip_runtime.h>

#define N_NODES 20000
#define N_EDGES 320000
#define NPAD    20032
#define NTILES  313         // NPAD/64
#define BN_EPS  1e-5f
#define NBLK    79          // ceil(20000/256)
#define CVTB    416         // 106496 threads / 256 for weight conversion

using bf16x8 = __attribute__((ext_vector_type(8))) short;
using f32x4  = __attribute__((ext_vector_type(4))) float;

__device__ __forceinline__ float bf2f(ushort u) {
  union { unsigned i; float f; } t; t.i = ((unsigned)u) << 16; return t.f;
}
__device__ __forceinline__ ushort f2bf(float f) {
  unsigned x = __float_as_uint(f);
  return (ushort)((x + 0x7fffu + ((x >> 16) & 1u)) >> 16);   // RNE
}

// bijective XCD-chunked swizzle (m204)
template <int NWG>
__device__ __forceinline__ int xcd_swz(int bid) {
  constexpr int Q = NWG / 8, R = NWG % 8;
  int xcd = bid & 7, pos = bid >> 3;
  return (xcd < R) ? (xcd * (Q + 1) + pos) : (R * (Q + 1) + (xcd - R) * Q + pos);
}

// ---------- fused: weights -> bf16 pool  +  degree count ----------
__global__ void k_prep(const float* s0, const float* s1, const float* s2,
                       const float* s3, const float* s4, const float* s5,
                       const float* s6, const float* s7, const float* s8,
                       const float* s9, ushort* __restrict__ wdst,
                       const int* __restrict__ edst, int* __restrict__ deg) {
  int b = blockIdx.x;
  if (b < CVTB) {
    int e = (b * 256 + threadIdx.x) * 4;
    if (e >= 425984) return;
    const float* s; int off;
    if      (e < 16384)  { s = s0; off = e; }
    else if (e < 49152)  { s = s1; off = e - 16384; }
    else if (e < 81920)  { s = s2; off = e - 49152; }
    else if (e < 147456) { s = s3; off = e - 81920; }
    else if (e < 212992) { s = s4; off = e - 147456; }
    else if (e < 278528) { s = s5; off = e - 212992; }
    else if (e < 344064) { s = s6; off = e - 278528; }
    else if (e < 376832) { s = s7; off = e - 344064; }
    else if (e < 409600) { s = s8; off = e - 376832; }
    else                 { s = s9; off = e - 409600; }
    float4 v = *(const float4*)(s + off);
    wdst[e + 0] = f2bf(v.x); wdst[e + 1] = f2bf(v.y);
    wdst[e + 2] = f2bf(v.z); wdst[e + 3] = f2bf(v.w);
  } else {
    int t = (b - CVTB) * 256 + threadIdx.x;
    if (t < N_EDGES) {
      unsigned d = (unsigned)edst[t];
      if (d < N_NODES) atomicAdd(&deg[d], 1);
    }
  }
}

// ---------- CSR scan ----------
__global__ void k_scanA(const int* __restrict__ deg, int* __restrict__ part,
                        int* __restrict__ bsum) {
  __shared__ int buf[256];
  int i = blockIdx.x * 256 + threadIdx.x;
  int v = (i < N_NODES) ? deg[i] : 0;
  buf[threadIdx.x] = v;
  __syncthreads();
  #pragma unroll
  for (int s = 1; s < 256; s <<= 1) {
    int t = (threadIdx.x >= s) ? buf[threadIdx.x - s] : 0;
    __syncthreads();
    buf[threadIdx.x] += t;
    __syncthreads();
  }
  if (i < N_NODES) part[i] = buf[threadIdx.x];
  if (threadIdx.x == 255) bsum[blockIdx.x] = buf[255];
}

__global__ void k_scanC(const int* __restrict__ deg, const int* __restrict__ part,
                        const int* __restrict__ bsum, int* __restrict__ rowptr,
                        int* __restrict__ cursor, float* __restrict__ inv) {
  __shared__ int soff;
  if (threadIdx.x == 0) {
    int o = 0;
    for (int b = 0; b < blockIdx.x; ++b) o += bsum[b];
    soff = o;
  }
  __syncthreads();
  int i = blockIdx.x * 256 + threadIdx.x;
  if (i >= N_NODES) return;
  int r1 = soff + part[i];
  int d = deg[i];
  rowptr[i + 1] = r1;
  cursor[i] = r1 - d;
  if (i == 0) rowptr[0] = 0;
  inv[i] = 1.0f / (float)max(d, 1);
}

__global__ void k_fill(const int* __restrict__ src, const int* __restrict__ dst,
                       int* __restrict__ cursor, int* __restrict__ col) {
  int e = blockIdx.x * blockDim.x + threadIdx.x;
  if (e >= N_EDGES) return;
  unsigned d = (unsigned)dst[e];
  if (d >= N_NODES) return;
  int p = atomicAdd(&cursor[d], 1);
  col[p] = src[e];
}

// ---------- gather-mean; BN in-register from raw stats; deep ILP ----------
template <int DIM, bool BN>
__global__ __launch_bounds__(256) void k_gather(
    const ushort* __restrict__ z, const int* __restrict__ rowptr,
    const int* __restrict__ col, const float* __restrict__ inv,
    const float* __restrict__ stats, const float* __restrict__ gamma,
    const float* __restrict__ beta, ushort* __restrict__ mean) {
  constexpr int LPR = DIM / 8;
  constexpr int NPW = 64 / LPR;
  int node = blockIdx.x * 4 + (threadIdx.x >> 6);
  if (node >= N_NODES) return;
  int lane = threadIdx.x & 63;
  int grp = lane / LPR;
  int sub = lane % LPR;
  float sc[8], sh[8];
  if constexpr (BN) {
    #pragma unroll
    for (int k = 0; k < 8; ++k) {
      int c = sub * 8 + k;
      float m = stats[c] * (1.0f / N_NODES);
      float var = stats[256 + c] * (1.0f / N_NODES) - m * m;
      float rs = rsqrtf(var + BN_EPS);
      sc[k] = rs * gamma[c];
      sh[k] = beta[c] - m * sc[k];
    }
  }
  float acc[8] = {};
  int r0 = rowptr[node], r1 = rowptr[node + 1];
  #pragma unroll 4
  for (int j = r0; j < r1; j += NPW) {
    int jj = j + grp;
    bool val = jj < r1;
    int nb = val ? col[jj] : 0;
    bf16x8 v = *(const bf16x8*)(z + (size_t)nb * DIM + sub * 8);
    float w = val ? 1.f : 0.f;
    #pragma unroll
    for (int k = 0; k < 8; ++k) {
      float f = bf2f((ushort)v[k]);
      if constexpr (BN) f = fmaxf(f * sc[k] + sh[k], 0.f);
      acc[k] += f * w;
    }
  }
  #pragma unroll
  for (int k = 0; k < 8; ++k) {
    if constexpr (NPW == 4) acc[k] += __shfl_xor(acc[k], 16);
    acc[k] += __shfl_xor(acc[k], 32);
  }
  if (grp == 0) {
    float iv = inv[node];
    bf16x8 o;
    #pragma unroll
    for (int k = 0; k < 8; ++k) o[k] = (short)f2bf(acc[k] * iv);
    *(bf16x8*)(mean + (size_t)node * DIM + sub * 8) = o;
  }
}

// ======================= GEMM building blocks =======================
template <int DIN>
__device__ __forceinline__ void stage_w(const ushort* __restrict__ Wsrc, char* Wt) {
  constexpr int LOGR = (DIN == 256) ? 9 : 8;
  const char* g = (const char*)Wsrc;
  #pragma unroll
  for (int i = 0; i < (64 * DIN * 2) / 4096; ++i) {
    int p = i * 4096 + threadIdx.x * 16;
    int row = p >> LOGR;
    bf16x8 v = *(const bf16x8*)(g + p);
    *(bf16x8*)(Wt + (p ^ ((row & 7) << 4))) = v;
  }
}

template <bool AF32, int DIN>
__device__ __forceinline__ void load_a(const void* __restrict__ A,
                                       int arow, int lb, bf16x8* af) {
  #pragma unroll
  for (int kk = 0; kk < DIN / 32; ++kk) {
    if constexpr (AF32) {
      const float* ap = (const float*)A + (size_t)arow * DIN + kk * 32 + lb * 8;
      float4 u = *(const float4*)ap;
      float4 v = *(const float4*)(ap + 4);
      bf16x8 a;
      a[0] = (short)f2bf(u.x); a[1] = (short)f2bf(u.y);
      a[2] = (short)f2bf(u.z); a[3] = (short)f2bf(u.w);
      a[4] = (short)f2bf(v.x); a[5] = (short)f2bf(v.y);
      a[6] = (short)f2bf(v.z); a[7] = (short)f2bf(v.w);
      af[kk] = a;
    } else {
      af[kk] = *(const bf16x8*)((const ushort*)A + (size_t)arow * DIN + kk * 32 + lb * 8);
    }
  }
}

template <int DIN>
__device__ __forceinline__ void apply_bn(bf16x8* af, const float* bnp, int lb) {
  #pragma unroll
  for (int kk = 0; kk < DIN / 32; ++kk) {
    int c0 = kk * 32 + lb * 8;
    float4 s0 = *(const float4*)(bnp + c0);
    float4 s1 = *(const float4*)(bnp + c0 + 4);
    float4 h0 = *(const float4*)(bnp + 256 + c0);
    float4 h1 = *(const float4*)(bnp + 256 + c0 + 4);
    bf16x8 r = af[kk];
    r[0] = (short)f2bf(fmaxf(bf2f((ushort)r[0]) * s0.x + h0.x, 0.f));
    r[1] = (short)f2bf(fmaxf(bf2f((ushort)r[1]) * s0.y + h0.y, 0.f));
    r[2] = (short)f2bf(fmaxf(bf2f((ushort)r[2]) * s0.z + h0.z, 0.f));
    r[3] = (short)f2bf(fmaxf(bf2f((ushort)r[3]) * s0.w + h0.w, 0.f));
    r[4] = (short)f2bf(fmaxf(bf2f((ushort)r[4]) * s1.x + h1.x, 0.f));
    r[5] = (short)f2bf(fmaxf(bf2f((ushort)r[5]) * s1.y + h1.y, 0.f));
    r[6] = (short)f2bf(fmaxf(bf2f((ushort)r[6]) * s1.z + h1.z, 0.f));
    r[7] = (short)f2bf(fmaxf(bf2f((ushort)r[7]) * s1.w + h1.w, 0.f));
    af[kk] = r;
  }
}

__device__ __forceinline__ void prep_bn_lds(const float* __restrict__ stats,
                                            const float* __restrict__ gamma,
                                            const float* __restrict__ beta,
                                            float* bnps) {
  int c = threadIdx.x;
  float m = stats[c] * (1.0f / N_NODES);
  float var = stats[256 + c] * (1.0f / N_NODES) - m * m;
  float rs = rsqrtf(var + BN_EPS);
  float scv = rs * gamma[c];
  bnps[c] = scv;
  bnps[256 + c] = beta[c] - m * scv;
}

template <int DIN>
__device__ __forceinline__ void compute(const bf16x8* af, const char* Wt,
                                        int la, int lb, f32x4* acc) {
  constexpr int LOGR = (DIN == 256) ? 9 : 8;
  #pragma unroll
  for (int kk = 0; kk < DIN / 32; ++kk) {
    #pragma unroll
    for (int nf = 0; nf < 4; ++nf) {
      int r = nf * 16 + la;
      int ad = (r << LOGR) + (kk * 32 + lb * 8) * 2;
      ad ^= ((r & 7) << 4);
      bf16x8 b = *(const bf16x8*)(Wt + ad);
      acc[nf] = __builtin_amdgcn_mfma_f32_16x16x32_bf16(af[kk], b, acc[nf], 0, 0, 0);
    }
  }
}

// 1D grid GY*NTILES, XCD-chunked; round-19 structure.
template <bool AF32, bool CF32, int DIN, int DOUT, bool DUAL, bool BNA2, bool STATS,
          bool SAMEW, int GY>
__global__ __launch_bounds__(256) void k_gemm(
    const void* __restrict__ A1v, const ushort* __restrict__ W1,
    const void* __restrict__ A2v, const ushort* __restrict__ W2,
    const float* __restrict__ bias, const float* __restrict__ bnstats,
    const float* __restrict__ gamma, const float* __restrict__ beta,
    float* __restrict__ stats, void* __restrict__ Cv, int Mstore)
{
  constexpr bool BOTHW = DUAL && !SAMEW && (DIN == 128);
  constexpr int WTB = 64 * DIN * 2;
  __shared__ __align__(16) char Wt[(BOTHW ? 2 : 1) * WTB];
  __shared__ float sbuf[64], qbuf[64];
  __shared__ float bnps[BNA2 ? 512 : 4];

  int orig = xcd_swz<GY * NTILES>(blockIdx.x);
  int bx = orig / GY, by = orig % GY;

  int lane = threadIdx.x & 63, wid = threadIdx.x >> 6;
  int la = lane & 15, lb = lane >> 4;
  int rowBase = bx * 64 + wid * 16;
  int colBase = by * 64;
  int arow = rowBase + la; if (arow >= N_NODES) arow = N_NODES - 1;

  if constexpr (STATS) {
    if (threadIdx.x < 64) { sbuf[threadIdx.x] = 0.f; qbuf[threadIdx.x] = 0.f; }
  }
  if constexpr (BNA2) prep_bn_lds(bnstats, gamma, beta, bnps);

  f32x4 acc[4];
  #pragma unroll
  for (int i = 0; i < 4; ++i) acc[i] = {0.f, 0.f, 0.f, 0.f};

  bf16x8 af[DIN / 32];
  load_a<AF32, DIN>(A1v, arow, lb, af);
  stage_w<DIN>(W1 + (size_t)colBase * DIN, Wt);
  if constexpr (BOTHW) stage_w<DIN>(W2 + (size_t)colBase * DIN, Wt + WTB);
  __syncthreads();
  compute<DIN>(af, Wt, la, lb, acc);

  if constexpr (DUAL) {
    if constexpr (BOTHW) {
      load_a<false, DIN>(A2v, arow, lb, af);
      if constexpr (BNA2) apply_bn<DIN>(af, bnps, lb);
      compute<DIN>(af, Wt + WTB, la, lb, acc);
    } else if constexpr (SAMEW) {
      load_a<false, DIN>(A2v, arow, lb, af);
      if constexpr (BNA2) apply_bn<DIN>(af, bnps, lb);
      compute<DIN>(af, Wt, la, lb, acc);
    } else {
      __syncthreads();
      load_a<false, DIN>(A2v, arow, lb, af);
      stage_w<DIN>(W2 + (size_t)colBase * DIN, Wt);
      if constexpr (BNA2) apply_bn<DIN>(af, bnps, lb);
      __syncthreads();
      compute<DIN>(af, Wt, la, lb, acc);
    }
  }

  // C/D layout: col = lane&15, row = (lane>>4)*4 + reg
  float colsum[4] = {}, colsq[4] = {};
  #pragma unroll
  for (int nf = 0; nf < 4; ++nf) {
    int col = colBase + nf * 16 + la;
    float bv = bias ? bias[col] : 0.0f;
    #pragma unroll
    for (int i = 0; i < 4; ++i) {
      int row = rowBase + lb * 4 + i;
      float o = acc[nf][i] + bv;
      if (row < Mstore) {
        if constexpr (CF32) ((float*)Cv)[(size_t)row * DOUT + col] = o;
        else                ((ushort*)Cv)[(size_t)row * DOUT + col] = f2bf(o);
      }
      if constexpr (STATS) {
        if (row < N_NODES) { colsum[nf] += o; colsq[nf] += o * o; }
      }
    }
  }

  if constexpr (STATS) {
    #pragma unroll
    for (int nf = 0; nf < 4; ++nf) {
      float sv = colsum[nf], qv = colsq[nf];
      sv += __shfl_xor(sv, 16); qv += __shfl_xor(qv, 16);
      sv += __shfl_xor(sv, 32); qv += __shfl_xor(qv, 32);
      if (lb == 0) { atomicAdd(&sbuf[nf * 16 + la], sv); atomicAdd(&qbuf[nf * 16 + la], qv); }
    }
    __syncthreads();
    if (threadIdx.x < 64)        atomicAdd(&stats[colBase + threadIdx.x], sbuf[threadIdx.x]);
    else if (threadIdx.x < 128)  atomicAdd(&stats[256 + colBase + threadIdx.x - 64], qbuf[threadIdx.x - 64]);
  }
}

// --------- layer-3 PQ GEMM: P = BN(z)@Wl^T, Q = BN(z)@Wr^T + bl ---------
__global__ __launch_bounds__(256) void k_gemm_pq(
    const ushort* __restrict__ z, const ushort* __restrict__ Wl,
    const ushort* __restrict__ Wr, const float* __restrict__ bl,
    const float* __restrict__ bnstats, const float* __restrict__ gamma,
    const float* __restrict__ beta, ushort* __restrict__ P, ushort* __restrict__ Q)
{
  constexpr int DIN = 256, DOUT = 128;
  __shared__ __align__(16) char Wt[64 * DIN * 2];
  __shared__ float bnps[512];
  int lane = threadIdx.x & 63, wid = threadIdx.x >> 6;
  int la = lane & 15, lb = lane >> 4;
  int rowBase = blockIdx.y * 64 + wid * 16;
  int colBase = blockIdx.x * 64;
  int arow = rowBase + la; if (arow >= N_NODES) arow = N_NODES - 1;

  prep_bn_lds(bnstats, gamma, beta, bnps);

  bf16x8 af[DIN / 32];
  load_a<false, DIN>(z, arow, lb, af);
  stage_w<DIN>(Wl + (size_t)colBase * DIN, Wt);
  __syncthreads();
  apply_bn<DIN>(af, bnps, lb);

  f32x4 acc[4];
  #pragma unroll
  for (int i = 0; i < 4; ++i) acc[i] = {0.f, 0.f, 0.f, 0.f};
  compute<DIN>(af, Wt, la, lb, acc);
  #pragma unroll
  for (int nf = 0; nf < 4; ++nf) {
    int col = colBase + nf * 16 + la;
    #pragma unroll
    for (int i = 0; i < 4; ++i) {
      int row = rowBase + lb * 4 + i;
      if (row < N_NODES) P[(size_t)row * DOUT + col] = f2bf(acc[nf][i]);
    }
  }

  __syncthreads();
  stage_w<DIN>(Wr + (size_t)colBase * DIN, Wt);
  __syncthreads();
  #pragma unroll
  for (int i = 0; i < 4; ++i) acc[i] = {0.f, 0.f, 0.f, 0.f};
  compute<DIN>(af, Wt, la, lb, acc);
  #pragma unroll
  for (int nf = 0; nf < 4; ++nf) {
    int col = colBase + nf * 16 + la;
    float bv = bl[col];
    #pragma unroll
    for (int i = 0; i < 4; ++i) {
      int row = rowBase + lb * 4 + i;
      if (row < N_NODES) Q[(size_t)row * DOUT + col] = f2bf(acc[nf][i] + bv);
    }
  }
}

extern "C" void kernel_launch(void* const* d_in, const int* in_sizes, int n_in,
                              void* d_out, int out_size, void* d_ws, size_t ws_size,
                              hipStream_t stream) {
  const float* x    = (const float*)d_in[0];
  const int*   ei   = (const int*)d_in[1];
  const float* encW = (const float*)d_in[2];
  const float* encb = (const float*)d_in[3];
  const float* Wl0  = (const float*)d_in[4];
  const float* bl0  = (const float*)d_in[5];
  const float* Wr0  = (const float*)d_in[6];
  const float* Wl1  = (const float*)d_in[7];
  const float* bl1  = (const float*)d_in[8];
  const float* Wr1  = (const float*)d_in[9];
  const float* Wl2  = (const float*)d_in[10];
  const float* bl2  = (const float*)d_in[11];
  const float* Wr2  = (const float*)d_in[12];
  const float* Wl3  = (const float*)d_in[13];
  const float* bl3  = (const float*)d_in[14];
  const float* Wr3  = (const float*)d_in[15];
  const float* g0   = (const float*)d_in[16];
  const float* b0   = (const float*)d_in[17];
  const float* g1   = (const float*)d_in[18];
  const float* b1   = (const float*)d_in[19];
  const float* g2   = (const float*)d_in[20];
  const float* b2   = (const float*)d_in[21];
  const float* decW = (const float*)d_in[22];
  const float* decb = (const float*)d_in[23];

  const int* src = ei;
  const int* dst = ei + N_EDGES;

  char* ws = (char*)d_ws;
  size_t off = 0;
  auto alloc = [&](size_t bytes) { char* p = ws + off; off += (bytes + 255) & ~255ull; return p; };
  ushort* bufA   = (ushort*)alloc((size_t)NPAD * 256 * 2);
  ushort* bufB   = (ushort*)alloc((size_t)NPAD * 256 * 2);
  ushort* mean   = (ushort*)alloc((size_t)NPAD * 256 * 2);
  int*    deg    = (int*)   alloc((size_t)N_NODES * 4);    // deg + stats adjacent:
  float*  stats  = (float*) alloc(3 * 512 * 4);            // single memset covers both
  int*    part   = (int*)   alloc((size_t)N_NODES * 4);
  int*    bsum   = (int*)   alloc(128 * 4);
  int*    rowptr = (int*)   alloc((size_t)(N_NODES + 1) * 4);
  int*    cursor = (int*)   alloc((size_t)N_NODES * 4);
  int*    colidx = (int*)   alloc((size_t)N_EDGES * 4);
  float*  inv    = (float*) alloc((size_t)N_NODES * 4);
  ushort* wpool  = (ushort*)alloc(425984 * 2);

  float* stats0 = stats, *stats1 = stats + 512, *stats2 = stats + 1024;

  const ushort* wEnc = wpool;
  const ushort* wL0  = wpool + 16384;
  const ushort* wR0  = wpool + 49152;
  const ushort* wL1  = wpool + 81920;
  const ushort* wR1  = wpool + 147456;
  const ushort* wL2  = wpool + 212992;
  const ushort* wR2  = wpool + 278528;
  const ushort* wL3  = wpool + 344064;
  const ushort* wR3  = wpool + 376832;
  const ushort* wDec = wpool + 409600;

  // ---- CSR build + weight convert (deg & stats zeroed in one memset) ----
  size_t degPad = ((size_t)N_NODES * 4 + 255) & ~255ull;
  hipMemsetAsync(deg, 0, degPad + 3 * 512 * 4, stream);
  k_prep<<<CVTB + (N_EDGES + 255) / 256, 256, 0, stream>>>(
      encW, Wl0, Wr0, Wl1, Wr1, Wl2, Wr2, Wl3, Wr3, decW, wpool, dst, deg);
  k_scanA<<<NBLK, 256, 0, stream>>>(deg, part, bsum);
  k_scanC<<<NBLK, 256, 0, stream>>>(deg, part, bsum, rowptr, cursor, inv);
  k_fill<<<(N_EDGES + 255) / 256, 256, 0, stream>>>(src, dst, cursor, colidx);

  const int GGRID = NTILES;   // 313
  const int NGB = (N_NODES + 3) / 4;

  // encoder: e(bufA) = x @ encW^T + encb  (f32 A, bf16 C)
  k_gemm<true, false, 128, 128, false, false, false, false, 2>
      <<<2 * GGRID, 256, 0, stream>>>(
      x, wEnc, nullptr, nullptr, encb, nullptr, nullptr, nullptr, nullptr,
      bufA, N_NODES);

  // SAGE0: h0(bufB) = mean(e)@Wl0 + bl0 + e@Wr0 ; stats0  (BOTHW)
  k_gather<128, false><<<NGB, 256, 0, stream>>>(
      bufA, rowptr, colidx, inv, nullptr, nullptr, nullptr, mean);
  k_gemm<false, false, 128, 256, true, false, true, false, 4>
      <<<4 * GGRID, 256, 0, stream>>>(
      mean, wL0, bufA, wR0, bl0, nullptr, nullptr, nullptr, stats0, bufB, N_NODES);

  // SAGE1: z1 = BN0(h0); h1(bufA) ; stats1
  k_gather<256, true><<<NGB, 256, 0, stream>>>(
      bufB, rowptr, colidx, inv, stats0, g0, b0, mean);
  k_gemm<false, false, 256, 256, true, true, true, false, 4>
      <<<4 * GGRID, 256, 0, stream>>>(
      mean, wL1, bufB, wR1, bl1, stats0, g0, b0, stats1, bufA, N_NODES);

  // SAGE2: h2(bufB) ; stats2
  k_gather<256, true><<<NGB, 256, 0, stream>>>(
      bufA, rowptr, colidx, inv, stats1, g1, b1, mean);
  k_gemm<false, false, 256, 256, true, true, true, false, 4>
      <<<4 * GGRID, 256, 0, stream>>>(
      mean, wL2, bufA, wR2, bl2, stats1, g1, b1, stats2, bufB, N_NODES);

  // SAGE3 re-associated: P = z3@Wl3^T, Q = z3@Wr3^T + bl3  (z3 = BN2(h2))
  ushort* P = mean;                          // NPAD x 128
  ushort* Q = mean + (size_t)NPAD * 128;     // NPAD x 128
  k_gemm_pq<<<dim3(2, GGRID), 256, 0, stream>>>(bufB, wL3, wR3, bl3,
                                                stats2, g2, b2, P, Q);

  // meanP(bufA) = gather-mean of P (128-dim)
  k_gather<128, false><<<NGB, 256, 0, stream>>>(
      P, rowptr, colidx, inv, nullptr, nullptr, nullptr, bufA);

  // decoder: d_out = (meanP + Q) @ decW^T + decb  (same-W dual, f32 out)
  k_gemm<false, true, 128, 128, true, false, false, true, 2>
      <<<2 * GGRID, 256, 0, stream>>>(
      bufA, wDec, Q, nullptr, decb, nullptr, nullptr, nullptr, nullptr,
      (float*)d_out, N_NODES);
}